// Round 8
// baseline (198.249 us; speedup 1.0000x reference)
//
#include <hip/hip_runtime.h>
#include <math.h>

#define B_ 4
#define L_ 4096
#define D_ 256
#define A_ 64
#define M_ (B_*L_)   // 16384 flat rows

typedef _Float16 half4 __attribute__((ext_vector_type(4)));
typedef _Float16 half8 __attribute__((ext_vector_type(8)));
typedef __attribute__((ext_vector_type(4))) float floatx4;

__device__ __forceinline__ unsigned short f2h_(float f) {
    _Float16 h = (_Float16)f;
    return __builtin_bit_cast(unsigned short, h);
}

// ---------------------------------------------------------------------------
// wconv: W f32 [256][64] -> W^T fp16 [64][256]. Wq scaled by 1/ln2 (exp2
// softmax domain). grid (3), block 256.
// ---------------------------------------------------------------------------
__global__ __launch_bounds__(256) void wconv_kernel(
    const float* __restrict__ Wq, const float* __restrict__ Wk,
    const float* __restrict__ Wv, unsigned short* __restrict__ wt)
{
    const int w = blockIdx.x, t = threadIdx.x;
    const float* W = (w == 0) ? Wq : (w == 1) ? Wk : Wv;
    unsigned short* o = wt + w * A_ * D_;
    const float scale = (w == 0) ? 1.44269504f : 1.0f;
    __shared__ float T[A_ * 260];
    #pragma unroll
    for (int p = 0; p < 16; ++p) {
        int idx = p * 256 + t;
        int d = idx >> 4, a4 = (idx & 15) * 4;
        float4 v = *(const float4*)(W + d * A_ + a4);
        T[(a4 + 0) * 260 + d] = v.x * scale;
        T[(a4 + 1) * 260 + d] = v.y * scale;
        T[(a4 + 2) * 260 + d] = v.z * scale;
        T[(a4 + 3) * 260 + d] = v.w * scale;
    }
    __syncthreads();
    const int a = t >> 2, d0 = (t & 3) * 64;
    #pragma unroll
    for (int i = 0; i < 16; ++i) {
        float4 v = *(const float4*)(&T[a * 260 + d0 + 4 * i]);
        ushort4 s;
        s.x = f2h_(v.x); s.y = f2h_(v.y); s.z = f2h_(v.z); s.w = f2h_(v.w);
        *(ushort4*)(o + a * D_ + d0 + 4 * i) = s;
    }
}

// ---------------------------------------------------------------------------
// proj (R5 known-good): one block per 32 x-rows computes ALL 3 projections.
// grid (M/32), block 384 = 6 waves (w = wid>>1, mt = wid&1).
// q/k fp16 [M][64]; v fp16 TRANSPOSED [B][64][L] (64B-aligned line stores).
// ---------------------------------------------------------------------------
__global__ __launch_bounds__(384) void proj_kernel(
    const float* __restrict__ x,           // [M][256] f32
    const unsigned short* __restrict__ wt, // [3][64][256] fp16 (W^T)
    unsigned short* __restrict__ qo,
    unsigned short* __restrict__ ko,
    unsigned short* __restrict__ vto)
{
    __shared__ __align__(16) unsigned short Xh[32 * 264];   // 16.5 KB
    __shared__ __align__(16) unsigned short Cst[6 * 1536];  // 18 KB
    const int t = threadIdx.x, m0 = blockIdx.x * 32;

    #pragma unroll
    for (int p = 0; p < 6; ++p) {
        int idx = p * 384 + t;
        if (idx < 2048) {
            int row = idx >> 6, col = (idx & 63) * 4;
            float4 v = *(const float4*)(x + (size_t)(m0 + row) * D_ + col);
            ushort4 s;
            s.x = f2h_(v.x); s.y = f2h_(v.y); s.z = f2h_(v.z); s.w = f2h_(v.w);
            *(ushort4*)(Xh + row * 264 + col) = s;
        }
    }
    __syncthreads();

    const int wid = t >> 6, lane = t & 63, c = lane & 15, g = lane >> 4;
    const int w = wid >> 1, mt = wid & 1;

    half8 xa[8];
    #pragma unroll
    for (int s = 0; s < 8; ++s)
        xa[s] = *(const half8*)(Xh + (16 * mt + c) * 264 + 32 * s + 8 * g);

    const unsigned short* wsrc = wt + w * A_ * D_;
    unsigned short* Cw = Cst + wid * 1536;
    #pragma unroll
    for (int nt = 0; nt < 4; ++nt) {
        floatx4 acc = {0.f, 0.f, 0.f, 0.f};
        #pragma unroll
        for (int s = 0; s < 8; ++s) {
            half8 wb = *(const half8*)(wsrc + (16 * nt + c) * D_ + 32 * s + 8 * g);
            acc = __builtin_amdgcn_mfma_f32_16x16x32_f16(xa[s], wb, acc, 0, 0, 0);
        }
        if (w < 2) {
            #pragma unroll
            for (int r = 0; r < 4; ++r)
                Cw[(4 * g + r) * 72 + 16 * nt + c] = f2h_(acc[r]);      // [m16][72]
        } else {
            #pragma unroll
            for (int r = 0; r < 4; ++r)
                Cw[(16 * nt + c) * 24 + 4 * g + r] = f2h_(acc[r]);      // [a64][24]
        }
    }

    if (w < 2) {
        unsigned short* o = (w == 0) ? qo : ko;
        const int row16 = lane >> 2, seg = lane & 3;
        uint4 d0 = *(const uint4*)(Cw + row16 * 72 + seg * 16);
        uint4 d1 = *(const uint4*)(Cw + row16 * 72 + seg * 16 + 8);
        unsigned short* p = o + (size_t)(m0 + 16 * mt + row16) * A_ + seg * 16;
        *(uint4*)(p) = d0;
        *(uint4*)(p + 8) = d1;
    }
    __syncthreads();
    if (t < 256) {
        const int a = t >> 2, quarter = t & 3;
        const int o = quarter * 8, mtv = o >> 4, idx = o & 15;
        uint4 d = *(const uint4*)(Cst + (4 + mtv) * 1536 + a * 24 + idx);
        const int bb = m0 >> 12, l0 = m0 & (L_ - 1);
        *(uint4*)(vto + ((size_t)(bb * A_ + a)) * L_ + l0 + o) = d;
    }
}

// ---------------------------------------------------------------------------
// attn: paired q-tiles, no split-K, no partials. grid (64, B), block 512 =
// 8 waves = qsub(2, 16q each) x phase(4, kt = 4*it+ph). Block bx handles
// qtiles {127-bx, bx} sequentially: T sums to ~65 -> perfect balance, 256
// blocks = 1/CU, all CUs busy to the end.
// K: LDS 4-tile pad-72 staging, register-prefetched one round ahead.
// V: NO LDS -- per-wave register prefetch of next tile's 8B A-frags.
// S^T form (verified): QK^T A=K,B=Q -> S^T[key][q=c]; softmax per-lane q
// (exp2 domain, q pre-scaled 1/ln2); PV: A=V^T regs, B=P^T regs (K=16).
// Epilogue: 4-phase merge per qsub via LDS, normalized, direct store.
// ---------------------------------------------------------------------------
__global__ __launch_bounds__(512, 2) void attn_kernel(
    const unsigned short* __restrict__ qb,  // [B][L][64] fp16 (x 1/ln2)
    const unsigned short* __restrict__ kb,  // [B][L][64] fp16
    const unsigned short* __restrict__ vt,  // [B][64][L] fp16
    float* __restrict__ out)                // [B][L][64] f32
{
    __shared__ __align__(16) unsigned short smem[4 * 4608];  // 36 KB (K tiles / epilogue)

    const int t    = threadIdx.x;
    const int lane = t & 63;
    const int wid  = t >> 6;
    const int qsub = wid >> 2;
    const int ph   = wid & 3;
    const int c    = lane & 15;
    const int g    = lane >> 4;
    const int b    = blockIdx.y;
    const int bx   = blockIdx.x;

    const size_t base  = (size_t)b * L_ * A_;
    const size_t vbase = (size_t)b * A_ * L_;

    const int srow = t >> 3, sc8 = t & 7;   // staging map: 512 thr = one 8KB tile

    for (int p = 0; p < 2; ++p) {
        const int qt = (p == 0) ? (127 - bx) : bx;   // heavy tile first
        const int q0 = qt * 32;
        const int qrow0 = q0 + 16 * qsub;
        const int qme = qrow0 + c;
        const int T = (qt >> 1) + 1;
        const int nR = (T + 3) >> 2;

        half8 qf[2];
        {
            const unsigned short* qp = qb + base + (size_t)(qrow0 + c) * A_ + g * 8;
            qf[0] = *(const half8*)(qp);
            qf[1] = *(const half8*)(qp + 32);
        }

        floatx4 O4[4];
        #pragma unroll
        for (int at = 0; at < 4; ++at) O4[at] = (floatx4){0.f, 0.f, 0.f, 0.f};
        float m_ = -INFINITY, l_ = 0.f;

        __syncthreads();     // prior epilogue reads done before restaging
        // ---- prologue: stage K round 0; V regs for tile ph ----
        #pragma unroll
        for (int u = 0; u < 4; ++u) {
            if (u < T) {
                uint4 dK = *(const uint4*)(kb + base + ((size_t)(u << 6) * 64 + t * 8));
                *(uint4*)(smem + u * 4608 + srow * 72 + sc8 * 8) = dK;
            }
        }
        half4 vc[4][4], vn[4][4];
        if (ph < T) {
            const unsigned short* vp = vt + vbase + (ph << 6);
            #pragma unroll
            for (int at = 0; at < 4; ++at)
                #pragma unroll
                for (int nt = 0; nt < 4; ++nt)
                    vc[at][nt] = *(const half4*)(vp + (size_t)(16 * at + c) * L_ + 16 * nt + 4 * g);
        }

        for (int it = 0; it < nR; ++it) {
            __syncthreads();                 // round-it staging visible
            const int kt = 4 * it + ph;
            const bool pfk = (it + 1 < nR);
            uint4 nK[4];
            if (pfk) {                       // prefetch next K round -> VGPRs
                #pragma unroll
                for (int u = 0; u < 4; ++u) {
                    const int kts = 4 * (it + 1) + u;
                    if (kts < T)
                        nK[u] = *(const uint4*)(kb + base + ((size_t)(kts << 6) * 64 + t * 8));
                }
            }
            if (kt + 4 < T) {                // prefetch this wave's next V tile
                const unsigned short* vp = vt + vbase + ((kt + 4) << 6);
                #pragma unroll
                for (int at = 0; at < 4; ++at)
                    #pragma unroll
                    for (int nt = 0; nt < 4; ++nt)
                        vn[at][nt] = *(const half4*)(vp + (size_t)(16 * at + c) * L_ + 16 * nt + 4 * g);
            }

            if (kt < T) {
                const int k0 = kt << 6;
                const unsigned short* Kw = smem + ph * 4608;

                // ---- S^T = K . Q^T ----
                floatx4 S4[4];
                #pragma unroll
                for (int nt = 0; nt < 4; ++nt) S4[nt] = (floatx4){0.f, 0.f, 0.f, 0.f};
                #pragma unroll
                for (int s = 0; s < 2; ++s)
                    #pragma unroll
                    for (int nt = 0; nt < 4; ++nt) {
                        half8 kf = *(const half8*)(Kw + (16 * nt + c) * 72 + 32 * s + 8 * g);
                        S4[nt] = __builtin_amdgcn_mfma_f32_16x16x32_f16(kf, qf[s], S4[nt], 0, 0, 0);
                    }

                // ---- causal mask (only tile T-1 straddles diagonal) ----
                if (kt == T - 1) {
                    #pragma unroll
                    for (int nt = 0; nt < 4; ++nt)
                        #pragma unroll
                        for (int r = 0; r < 4; ++r)
                            if (k0 + 16 * nt + 4 * g + r > qme) S4[nt][r] = -INFINITY;
                }

                // ---- online softmax (exp2; per-lane q row) ----
                float tm = fmaxf(fmaxf(fmaxf(S4[0][0], S4[0][1]), fmaxf(S4[0][2], S4[0][3])),
                                 fmaxf(fmaxf(S4[1][0], S4[1][1]), fmaxf(S4[1][2], S4[1][3])));
                tm = fmaxf(tm, fmaxf(fmaxf(fmaxf(S4[2][0], S4[2][1]), fmaxf(S4[2][2], S4[2][3])),
                                     fmaxf(fmaxf(S4[3][0], S4[3][1]), fmaxf(S4[3][2], S4[3][3]))));
                tm = fmaxf(tm, __shfl_xor(tm, 16));
                tm = fmaxf(tm, __shfl_xor(tm, 32));
                const float mn  = fmaxf(m_, tm);
                const float mnc = fmaxf(mn, -3.0e38f);
                const float al  = exp2f(fminf(m_ - mnc, 0.f));
                float rs = 0.f;
                half4 pfr[4];
                #pragma unroll
                for (int nt = 0; nt < 4; ++nt) {
                    #pragma unroll
                    for (int r = 0; r < 4; ++r) {
                        float pv = exp2f(S4[nt][r] - mnc);
                        S4[nt][r] = pv;
                        rs += pv;
                    }
                    pfr[nt][0] = (_Float16)S4[nt][0];
                    pfr[nt][1] = (_Float16)S4[nt][1];
                    pfr[nt][2] = (_Float16)S4[nt][2];
                    pfr[nt][3] = (_Float16)S4[nt][3];
                }
                rs += __shfl_xor(rs, 16);
                rs += __shfl_xor(rs, 32);
                l_ = l_ * al + rs;
                m_ = mn;

                // ---- O^T = O^T*al + V^T . P^T (V from registers) ----
                #pragma unroll
                for (int at = 0; at < 4; ++at) {
                    O4[at] *= al;
                    #pragma unroll
                    for (int nt = 0; nt < 4; ++nt)
                        O4[at] = __builtin_amdgcn_mfma_f32_16x16x16f16(vc[at][nt], pfr[nt], O4[at], 0, 0, 0);
                }
                if (kt + 4 < T) {
                    #pragma unroll
                    for (int at = 0; at < 4; ++at)
                        #pragma unroll
                        for (int nt = 0; nt < 4; ++nt)
                            vc[at][nt] = vn[at][nt];
                }
            }

            __syncthreads();                 // all LDS reads of round it done
            if (pfk) {
                #pragma unroll
                for (int u = 0; u < 4; ++u)
                    if (4 * (it + 1) + u < T)
                        *(uint4*)(smem + u * 4608 + srow * 72 + sc8 * 8) = nK[u];
            }
        }

        // ---- epilogue: 4-phase merge per qsub, normalize, store ----
        float4* Obuf = (float4*)smem;                    // 8x4x64 float4 = 32 KB
        float2* mlq  = (float2*)((char*)smem + 32768);   // 8x16 float2
        #pragma unroll
        for (int at = 0; at < 4; ++at) {
            float4 v; v.x = O4[at][0]; v.y = O4[at][1]; v.z = O4[at][2]; v.w = O4[at][3];
            Obuf[wid * 256 + at * 64 + lane] = v;
        }
        if (g == 0) { float2 ml; ml.x = m_; ml.y = l_; mlq[wid * 16 + c] = ml; }
        __syncthreads();
        {
            const int q = t >> 4, seg = t & 15;          // q row 0..31, a-seg 0..15
            const int qs = q >> 4, cc = q & 15;
            const int at = seg >> 2, gg = seg & 3;
            const float2 A0 = mlq[(qs * 4 + 0) * 16 + cc];
            const float2 A1 = mlq[(qs * 4 + 1) * 16 + cc];
            const float2 A2 = mlq[(qs * 4 + 2) * 16 + cc];
            const float2 A3 = mlq[(qs * 4 + 3) * 16 + cc];
            const float mf = fmaxf(fmaxf(A0.x, A1.x), fmaxf(A2.x, A3.x));  // finite
            const float w0 = exp2f(A0.x - mf), w1 = exp2f(A1.x - mf);
            const float w2 = exp2f(A2.x - mf), w3 = exp2f(A3.x - mf);
            const float inv = 1.f / (w0 * A0.y + w1 * A1.y + w2 * A2.y + w3 * A3.y);
            const float4 o0 = Obuf[(qs * 4 + 0) * 256 + at * 64 + gg * 16 + cc];
            const float4 o1 = Obuf[(qs * 4 + 1) * 256 + at * 64 + gg * 16 + cc];
            const float4 o2 = Obuf[(qs * 4 + 2) * 256 + at * 64 + gg * 16 + cc];
            const float4 o3 = Obuf[(qs * 4 + 3) * 256 + at * 64 + gg * 16 + cc];
            float4 r;
            r.x = (o0.x * w0 + o1.x * w1 + o2.x * w2 + o3.x * w3) * inv;
            r.y = (o0.y * w0 + o1.y * w1 + o2.y * w2 + o3.y * w3) * inv;
            r.z = (o0.z * w0 + o1.z * w1 + o2.z * w2 + o3.z * w3) * inv;
            r.w = (o0.w * w0 + o1.w * w1 + o2.w * w2 + o3.w * w3) * inv;
            *(float4*)(out + base + (size_t)(q0 + q) * A_ + seg * 4) = r;
        }
    }
}

// ---------------------------------------------------------------------------
extern "C" void kernel_launch(void* const* d_in, const int* in_sizes, int n_in,
                              void* d_out, int out_size, void* d_ws, size_t ws_size,
                              hipStream_t stream) {
    const float* x  = (const float*)d_in[0];
    const float* Wq = (const float*)d_in[1];
    const float* Wk = (const float*)d_in[2];
    const float* Wv = (const float*)d_in[3];

    char* ws = (char*)d_ws;
    unsigned short* qb = (unsigned short*)(ws);                      // 2 MB
    unsigned short* kb = (unsigned short*)(ws + (2u << 20));         // 2 MB
    unsigned short* vt = (unsigned short*)(ws + (4u << 20));         // 2 MB
    unsigned short* wt = (unsigned short*)(ws + (6u << 20));         // 96 KB
    float* out = (float*)d_out;

    hipLaunchKernelGGL(wconv_kernel, dim3(3), dim3(256), 0, stream, Wq, Wk, Wv, wt);
    hipLaunchKernelGGL(proj_kernel, dim3(M_ / 32), dim3(384), 0, stream, x, wt, qb, kb, vt);
    hipLaunchKernelGGL(attn_kernel, dim3(64, B_), dim3(512), 0, stream, qb, kb, vt, out);
}

// Round 9
// 141.950 us; speedup vs baseline: 1.3966x; 1.3966x over previous
//
#include <hip/hip_runtime.h>
#include <math.h>

#define B_ 4
#define L_ 4096
#define D_ 256
#define A_ 64
#define M_ (B_*L_)   // 16384 flat rows

typedef _Float16 half4 __attribute__((ext_vector_type(4)));
typedef _Float16 half8 __attribute__((ext_vector_type(8)));
typedef __attribute__((ext_vector_type(4))) float floatx4;

__device__ __forceinline__ unsigned short f2h_(float f) {
    _Float16 h = (_Float16)f;
    return __builtin_bit_cast(unsigned short, h);
}

// ---------------------------------------------------------------------------
// wconv: W f32 [256][64] -> W^T fp16 [64][256]. Wq scaled by 1/ln2 (exp2
// softmax domain). grid (3), block 256.
// ---------------------------------------------------------------------------
__global__ __launch_bounds__(256) void wconv_kernel(
    const float* __restrict__ Wq, const float* __restrict__ Wk,
    const float* __restrict__ Wv, unsigned short* __restrict__ wt)
{
    const int w = blockIdx.x, t = threadIdx.x;
    const float* W = (w == 0) ? Wq : (w == 1) ? Wk : Wv;
    unsigned short* o = wt + w * A_ * D_;
    const float scale = (w == 0) ? 1.44269504f : 1.0f;
    __shared__ float T[A_ * 260];
    #pragma unroll
    for (int p = 0; p < 16; ++p) {
        int idx = p * 256 + t;
        int d = idx >> 4, a4 = (idx & 15) * 4;
        float4 v = *(const float4*)(W + d * A_ + a4);
        T[(a4 + 0) * 260 + d] = v.x * scale;
        T[(a4 + 1) * 260 + d] = v.y * scale;
        T[(a4 + 2) * 260 + d] = v.z * scale;
        T[(a4 + 3) * 260 + d] = v.w * scale;
    }
    __syncthreads();
    const int a = t >> 2, d0 = (t & 3) * 64;
    #pragma unroll
    for (int i = 0; i < 16; ++i) {
        float4 v = *(const float4*)(&T[a * 260 + d0 + 4 * i]);
        ushort4 s;
        s.x = f2h_(v.x); s.y = f2h_(v.y); s.z = f2h_(v.z); s.w = f2h_(v.w);
        *(ushort4*)(o + a * D_ + d0 + 4 * i) = s;
    }
}

// ---------------------------------------------------------------------------
// proj (R5 known-good): one block per 32 x-rows computes ALL 3 projections.
// grid (M/32), block 384 = 6 waves (w = wid>>1, mt = wid&1).
// q/k fp16 [M][64]; v fp16 TRANSPOSED [B][64][L] (64B-aligned line stores).
// ---------------------------------------------------------------------------
__global__ __launch_bounds__(384) void proj_kernel(
    const float* __restrict__ x,           // [M][256] f32
    const unsigned short* __restrict__ wt, // [3][64][256] fp16 (W^T)
    unsigned short* __restrict__ qo,
    unsigned short* __restrict__ ko,
    unsigned short* __restrict__ vto)
{
    __shared__ __align__(16) unsigned short Xh[32 * 264];   // 16.5 KB
    __shared__ __align__(16) unsigned short Cst[6 * 1536];  // 18 KB
    const int t = threadIdx.x, m0 = blockIdx.x * 32;

    #pragma unroll
    for (int p = 0; p < 6; ++p) {
        int idx = p * 384 + t;
        if (idx < 2048) {
            int row = idx >> 6, col = (idx & 63) * 4;
            float4 v = *(const float4*)(x + (size_t)(m0 + row) * D_ + col);
            ushort4 s;
            s.x = f2h_(v.x); s.y = f2h_(v.y); s.z = f2h_(v.z); s.w = f2h_(v.w);
            *(ushort4*)(Xh + row * 264 + col) = s;
        }
    }
    __syncthreads();

    const int wid = t >> 6, lane = t & 63, c = lane & 15, g = lane >> 4;
    const int w = wid >> 1, mt = wid & 1;

    half8 xa[8];
    #pragma unroll
    for (int s = 0; s < 8; ++s)
        xa[s] = *(const half8*)(Xh + (16 * mt + c) * 264 + 32 * s + 8 * g);

    const unsigned short* wsrc = wt + w * A_ * D_;
    unsigned short* Cw = Cst + wid * 1536;
    #pragma unroll
    for (int nt = 0; nt < 4; ++nt) {
        floatx4 acc = {0.f, 0.f, 0.f, 0.f};
        #pragma unroll
        for (int s = 0; s < 8; ++s) {
            half8 wb = *(const half8*)(wsrc + (16 * nt + c) * D_ + 32 * s + 8 * g);
            acc = __builtin_amdgcn_mfma_f32_16x16x32_f16(xa[s], wb, acc, 0, 0, 0);
        }
        if (w < 2) {
            #pragma unroll
            for (int r = 0; r < 4; ++r)
                Cw[(4 * g + r) * 72 + 16 * nt + c] = f2h_(acc[r]);      // [m16][72]
        } else {
            #pragma unroll
            for (int r = 0; r < 4; ++r)
                Cw[(16 * nt + c) * 24 + 4 * g + r] = f2h_(acc[r]);      // [a64][24]
        }
    }

    if (w < 2) {
        unsigned short* o = (w == 0) ? qo : ko;
        const int row16 = lane >> 2, seg = lane & 3;
        uint4 d0 = *(const uint4*)(Cw + row16 * 72 + seg * 16);
        uint4 d1 = *(const uint4*)(Cw + row16 * 72 + seg * 16 + 8);
        unsigned short* p = o + (size_t)(m0 + 16 * mt + row16) * A_ + seg * 16;
        *(uint4*)(p) = d0;
        *(uint4*)(p + 8) = d1;
    }
    __syncthreads();
    if (t < 256) {
        const int a = t >> 2, quarter = t & 3;
        const int o = quarter * 8, mtv = o >> 4, idx = o & 15;
        uint4 d = *(const uint4*)(Cst + (4 + mtv) * 1536 + a * 24 + idx);
        const int bb = m0 >> 12, l0 = m0 & (L_ - 1);
        *(uint4*)(vto + ((size_t)(bb * A_ + a)) * L_ + l0 + o) = d;
    }
}

// ---------------------------------------------------------------------------
// attn: R5 structure, FAT WAVES. grid (256, B): bx -> (qt = 127-(bx>>1),
// h = bx&1). Block = 128 thr = 2 waves = 2 key phases; EACH WAVE owns all
// 32 queries (2 subtiles of 16) -> K/V LDS fragments loaded once per tile
// feed 2x the MFMA (48/tile), halving barrier+LDS overhead per unit work.
// K/V staged 2 tiles/round in LDS (pad 72). Split-K halves [t0,t1) of
// T=(qt>>1)+1 tiles; in-block 2-phase merge -> unnormalized partial
// (O, m, l): h=0 -> out, h=1 -> po1. Final merge kernel combines.
// ---------------------------------------------------------------------------
__global__ __launch_bounds__(128) void attn_kernel(
    const unsigned short* __restrict__ qb,  // [B][L][64] fp16 (x 1/ln2)
    const unsigned short* __restrict__ kb,  // [B][L][64] fp16
    const unsigned short* __restrict__ vt,  // [B][64][L] fp16
    float* __restrict__ out,                // partial O for h=0
    float* __restrict__ po1,                // partial O for h=1
    float2* __restrict__ ml0,               // (m,l) h=0  [B*L]
    float2* __restrict__ ml1)               // (m,l) h=1  [B*L]
{
    __shared__ __align__(16) unsigned short smem[4 * 4608];  // 36 KB
    unsigned short* Ks = smem;
    unsigned short* Vs = smem + 2 * 4608;

    const int t    = threadIdx.x;
    const int lane = t & 63;
    const int ph   = t >> 6;          // wave = key phase
    const int c    = lane & 15;
    const int g    = lane >> 4;
    const int b    = blockIdx.y;
    const int bx   = blockIdx.x;
    const int qt   = 127 - (bx >> 1); // heavy q-tiles first
    const int h    = bx & 1;
    const int q0   = qt * 32;

    const size_t base  = (size_t)b * L_ * A_;
    const size_t vbase = (size_t)b * A_ * L_;

    // Q fragments for both subtiles (u: rows q0+16u+c)
    half8 qf[2][2];
    #pragma unroll
    for (int u = 0; u < 2; ++u) {
        const unsigned short* qp = qb + base + (size_t)(q0 + 16 * u + c) * A_ + g * 8;
        qf[u][0] = *(const half8*)(qp);
        qf[u][1] = *(const half8*)(qp + 32);
    }

    floatx4 O4[2][4];       // per subtile: O^T[a=16at+4g+r][q=c]
    float m_[2], l_[2];
    #pragma unroll
    for (int u = 0; u < 2; ++u) {
        #pragma unroll
        for (int at = 0; at < 4; ++at) O4[u][at] = (floatx4){0.f, 0.f, 0.f, 0.f};
        m_[u] = -INFINITY; l_[u] = 0.f;
    }

    const int T   = (qt >> 1) + 1;
    const int Th  = (T + 1) >> 1;
    const int t0  = h ? Th : 0;
    const int t1  = h ? T : Th;
    const int nIt = (t1 - t0 + 1) >> 1;
    const int Tm1 = T - 1;

    for (int it = 0; it < nIt; ++it) {
        __syncthreads();
        #pragma unroll
        for (int tile = 0; tile < 2; ++tile) {
            const int kts = t0 + 2 * it + tile;
            if (kts < t1) {
                const int k0s = kts << 6;
                #pragma unroll
                for (int i = 0; i < 4; ++i) {
                    const int cid = t + (i << 7);         // 0..511
                    const int row = cid >> 3, c8 = cid & 7;
                    uint4 dK = *(const uint4*)(kb + base + (size_t)k0s * 64 + cid * 8);
                    *(uint4*)(Ks + tile * 4608 + row * 72 + c8 * 8) = dK;
                    uint4 dV = *(const uint4*)(vt + vbase + (size_t)row * L_ + k0s + c8 * 8);
                    *(uint4*)(Vs + tile * 4608 + row * 72 + c8 * 8) = dV;
                }
            }
        }
        __syncthreads();

        const int kt = t0 + 2 * it + ph;
        if (kt >= t1) continue;          // loop-top barriers stay convergent
        const int k0 = kt << 6;
        const unsigned short* Kw = Ks + ph * 4608;
        const unsigned short* Vw = Vs + ph * 4608;

        // ---- S^T = K . Q^T for both subtiles (K frags loaded ONCE) ----
        floatx4 S4[2][4];
        #pragma unroll
        for (int u = 0; u < 2; ++u)
            #pragma unroll
            for (int nt = 0; nt < 4; ++nt) S4[u][nt] = (floatx4){0.f, 0.f, 0.f, 0.f};
        #pragma unroll
        for (int s = 0; s < 2; ++s)
            #pragma unroll
            for (int nt = 0; nt < 4; ++nt) {
                half8 kf = *(const half8*)(Kw + (16 * nt + c) * 72 + 32 * s + 8 * g);
                S4[0][nt] = __builtin_amdgcn_mfma_f32_16x16x32_f16(kf, qf[0][s], S4[0][nt], 0, 0, 0);
                S4[1][nt] = __builtin_amdgcn_mfma_f32_16x16x32_f16(kf, qf[1][s], S4[1][nt], 0, 0, 0);
            }

        // ---- causal mask: only global tile T-1 straddles the diagonal ----
        if (kt == Tm1) {
            #pragma unroll
            for (int u = 0; u < 2; ++u) {
                const int qme = q0 + 16 * u + c;
                #pragma unroll
                for (int nt = 0; nt < 4; ++nt)
                    #pragma unroll
                    for (int r = 0; r < 4; ++r)
                        if (k0 + 16 * nt + 4 * g + r > qme) S4[u][nt][r] = -INFINITY;
            }
        }

        // ---- online softmax per subtile (exp2 domain; per-lane q row) ----
        half4 pfr[2][4];
        float al[2];
        #pragma unroll
        for (int u = 0; u < 2; ++u) {
            float tm = fmaxf(fmaxf(fmaxf(S4[u][0][0], S4[u][0][1]), fmaxf(S4[u][0][2], S4[u][0][3])),
                             fmaxf(fmaxf(S4[u][1][0], S4[u][1][1]), fmaxf(S4[u][1][2], S4[u][1][3])));
            tm = fmaxf(tm, fmaxf(fmaxf(fmaxf(S4[u][2][0], S4[u][2][1]), fmaxf(S4[u][2][2], S4[u][2][3])),
                                 fmaxf(fmaxf(S4[u][3][0], S4[u][3][1]), fmaxf(S4[u][3][2], S4[u][3][3]))));
            tm = fmaxf(tm, __shfl_xor(tm, 16));
            tm = fmaxf(tm, __shfl_xor(tm, 32));
            const float mn  = fmaxf(m_[u], tm);
            const float mnc = fmaxf(mn, -3.0e38f);          // guard -inf - -inf
            al[u] = exp2f(fminf(m_[u] - mnc, 0.f));         // m=-inf -> 0
            float rs = 0.f;
            #pragma unroll
            for (int nt = 0; nt < 4; ++nt) {
                #pragma unroll
                for (int r = 0; r < 4; ++r) {
                    float pv = exp2f(S4[u][nt][r] - mnc);   // masked: exp2(-inf)=0
                    S4[u][nt][r] = pv;
                    rs += pv;
                }
                pfr[u][nt][0] = (_Float16)S4[u][nt][0];
                pfr[u][nt][1] = (_Float16)S4[u][nt][1];
                pfr[u][nt][2] = (_Float16)S4[u][nt][2];
                pfr[u][nt][3] = (_Float16)S4[u][nt][3];
            }
            rs += __shfl_xor(rs, 16);
            rs += __shfl_xor(rs, 32);
            l_[u] = l_[u] * al[u] + rs;
            m_[u] = mn;
        }

        // ---- PV: V frags loaded ONCE, feed both subtiles ----
        #pragma unroll
        for (int at = 0; at < 4; ++at) {
            O4[0][at] *= al[0];
            O4[1][at] *= al[1];
            #pragma unroll
            for (int nt = 0; nt < 4; ++nt) {
                half4 va = *(const half4*)(Vw + (16 * at + c) * 72 + 16 * nt + 4 * g);
                O4[0][at] = __builtin_amdgcn_mfma_f32_16x16x16f16(va, pfr[0][nt], O4[0][at], 0, 0, 0);
                O4[1][at] = __builtin_amdgcn_mfma_f32_16x16x16f16(va, pfr[1][nt], O4[1][at], 0, 0, 0);
            }
        }
    }

    // ---- in-block 2-phase merge; write unnormalized partial ----
    __syncthreads();
    float4* Obuf = (float4*)smem;               // [ph*2+u][at][lane] = 16 KB
    float2* mlq  = (float2*)((char*)smem + 16384);  // [ph*2+u][c]
    #pragma unroll
    for (int u = 0; u < 2; ++u) {
        #pragma unroll
        for (int at = 0; at < 4; ++at) {
            float4 v; v.x = O4[u][at][0]; v.y = O4[u][at][1];
            v.z = O4[u][at][2]; v.w = O4[u][at][3];
            Obuf[((ph * 2 + u) * 4 + at) * 64 + lane] = v;
        }
        if (g == 0) { float2 ml; ml.x = m_[u]; ml.y = l_[u]; mlq[(ph * 2 + u) * 16 + c] = ml; }
    }
    __syncthreads();
    {
        const int q = t >> 2, seg = t & 3;      // q row 0..31, 16 floats each
        const int u = q >> 4, cc = q & 15;
        const float2 A0 = mlq[(0 * 2 + u) * 16 + cc];
        const float2 A1 = mlq[(1 * 2 + u) * 16 + cc];
        const float mf = fmaxf(A0.x, A1.x);
        const float mc = fmaxf(mf, -3.0e38f);
        const float w0 = exp2f(A0.x - mc);      // -inf -> 0
        const float w1 = exp2f(A1.x - mc);
        const float ls = w0 * A0.y + w1 * A1.y;
        float res[16];
        #pragma unroll
        for (int j = 0; j < 16; ++j) {
            const int gg = j >> 2, r = j & 3;
            const float* e0 = (const float*)&Obuf[((0 * 2 + u) * 4 + seg) * 64 + gg * 16 + cc];
            const float* e1 = (const float*)&Obuf[((1 * 2 + u) * 4 + seg) * 64 + gg * 16 + cc];
            res[j] = w0 * e0[r] + w1 * e1[r];
        }
        float* PO = h ? po1 : out;
        float* p = PO + base + (size_t)(q0 + q) * A_ + seg * 16;
        #pragma unroll
        for (int v = 0; v < 4; ++v)
            *(float4*)(p + 4 * v) = make_float4(res[4*v], res[4*v+1], res[4*v+2], res[4*v+3]);
        if (seg == 0) {
            float2 ml; ml.x = mf; ml.y = ls;
            (h ? ml1 : ml0)[b * L_ + q0 + q] = ml;
        }
    }
}

// ---------------------------------------------------------------------------
// merge: final = (O0*w0 + O1*w1) / (l0*w0 + l1*w1). grid (1024), block 256.
// ---------------------------------------------------------------------------
__global__ __launch_bounds__(256) void merge_kernel(
    float* __restrict__ out, const float* __restrict__ po1,
    const float2* __restrict__ ml0, const float2* __restrict__ ml1)
{
    const int tg = blockIdx.x * 256 + threadIdx.x;   // 262144 float4s
    const int q = tg >> 4;
    const float2 a0 = ml0[q], a1 = ml1[q];
    const float mf = fmaxf(a0.x, a1.x);
    const float mc = fmaxf(mf, -3.0e38f);
    const float w0 = exp2f(a0.x - mc);
    const float w1 = exp2f(a1.x - mc);
    const float inv = 1.f / (w0 * a0.y + w1 * a1.y);
    float4 o0 = ((const float4*)out)[tg];
    float4 o1 = ((const float4*)po1)[tg];
    float4 r;
    r.x = (o0.x * w0 + o1.x * w1) * inv;
    r.y = (o0.y * w0 + o1.y * w1) * inv;
    r.z = (o0.z * w0 + o1.z * w1) * inv;
    r.w = (o0.w * w0 + o1.w * w1) * inv;
    ((float4*)out)[tg] = r;
}

// ---------------------------------------------------------------------------
extern "C" void kernel_launch(void* const* d_in, const int* in_sizes, int n_in,
                              void* d_out, int out_size, void* d_ws, size_t ws_size,
                              hipStream_t stream) {
    const float* x  = (const float*)d_in[0];
    const float* Wq = (const float*)d_in[1];
    const float* Wk = (const float*)d_in[2];
    const float* Wv = (const float*)d_in[3];

    char* ws = (char*)d_ws;
    unsigned short* qb = (unsigned short*)(ws);                      // 2 MB
    unsigned short* kb = (unsigned short*)(ws + (2u << 20));         // 2 MB
    unsigned short* vt = (unsigned short*)(ws + (4u << 20));         // 2 MB
    unsigned short* wt = (unsigned short*)(ws + (6u << 20));         // 96 KB (pad 128)
    float*  po1 = (float*) (ws + (6u << 20) + (128u << 10));         // 4 MB
    float2* ml0 = (float2*)(ws + (10u << 20) + (128u << 10));        // 128 KB
    float2* ml1 = (float2*)(ws + (10u << 20) + (256u << 10));        // 128 KB
    float* out = (float*)d_out;

    hipLaunchKernelGGL(wconv_kernel, dim3(3), dim3(256), 0, stream, Wq, Wk, Wv, wt);
    hipLaunchKernelGGL(proj_kernel, dim3(M_ / 32), dim3(384), 0, stream, x, wt, qb, kb, vt);
    hipLaunchKernelGGL(attn_kernel, dim3(256, B_), dim3(128), 0, stream,
                       qb, kb, vt, out, po1, ml0, ml1);
    hipLaunchKernelGGL(merge_kernel, dim3(1024), dim3(256), 0, stream, out, po1, ml0, ml1);
}